// Round 1
// baseline (366.455 us; speedup 1.0000x reference)
//
#include <hip/hip_runtime.h>

// Problem constants (fixed by reference)
#define N_B   8
#define H_DIM 64
#define W_DIM 64
#define HW    4096
#define C_DIM 256
#define G_G   4
#define GD_D  64
#define OMD   112   // OM_DIM
#define M_ROWS (N_B * HW)   // 32768

// ---------------------------------------------------------------------------
// Weight transposes: w_in_t[k][c], w_out_t[k][c], w_pw_t[c][o]
// ---------------------------------------------------------------------------
__global__ __launch_bounds__(256) void transpose_weights(
    const float* __restrict__ w_in, const float* __restrict__ w_out,
    const float* __restrict__ w_pw, float* __restrict__ w_in_t,
    float* __restrict__ w_out_t, float* __restrict__ w_pw_t) {
  int idx = blockIdx.x * 256 + threadIdx.x;
  if (idx < 65536) {
    int k = idx >> 8, c = idx & 255;
    w_in_t[idx] = w_in[c * 256 + k];
  } else if (idx < 131072) {
    int i = idx - 65536;
    int k = i >> 8, c = i & 255;
    w_out_t[i] = w_out[c * 256 + k];
  } else if (idx < 131072 + 256 * OMD) {
    int i = idx - 131072;
    int c = i / OMD, o = i % OMD;
    w_pw_t[i] = w_pw[o * 256 + c];
  }
}

// ---------------------------------------------------------------------------
// Depthwise 3x3 conv (zero pad), NHWC, one thread per (pixel, channel)
// ---------------------------------------------------------------------------
__global__ __launch_bounds__(256) void dwconv(
    const float* __restrict__ x, const float* __restrict__ w_dw,
    const float* __restrict__ b_dw, float* __restrict__ dw) {
  int idx = blockIdx.x * 256 + threadIdx.x;   // (pixel, c), 8.4M total
  int c  = idx & 255;
  int pp = idx >> 8;                           // global pixel 0..32767
  int n  = pp >> 12;
  int hw = pp & 4095;
  int h = hw >> 6, w = hw & 63;
  float acc = b_dw[c];
#pragma unroll
  for (int ky = 0; ky < 3; ++ky) {
    int iy = h + ky - 1;
    if (iy < 0 || iy > 63) continue;
#pragma unroll
    for (int kx = 0; kx < 3; ++kx) {
      int ix = w + kx - 1;
      if (ix < 0 || ix > 63) continue;
      acc += x[((size_t)(n << 12) + iy * 64 + ix) * 256 + c]
           * w_dw[(ky * 3 + kx) * 256 + c];
    }
  }
  dw[(size_t)idx] = acc;
}

// ---------------------------------------------------------------------------
// fp32 register-tiled GEMM: C[M,Nn] = A[M,K] * Bt[K,Nn] + bias[Nn]
// BM=128, BN=64, BK=16, 256 threads, 8x4 acc per thread.
// Requires: M % 128 == 0, K % 16 == 0, Nn % 4 == 0, A row stride == K.
// ---------------------------------------------------------------------------
__global__ __launch_bounds__(256) void gemm_bias(
    const float* __restrict__ A, const float* __restrict__ Bt,
    const float* __restrict__ bias, float* __restrict__ C,
    int Nn, int K) {
  const int BM = 128, BK = 16;
  __shared__ __align__(16) float As[BK][BM];   // [kk][row]
  __shared__ __align__(16) float Bs[BK][64];   // [kk][col]
  int tid = threadIdx.x;
  long rowBase = (long)blockIdx.x * BM;
  int colBase = blockIdx.y * 64;
  int tx = tid & 15, ty = tid >> 4;            // cols tx*4, rows ty*8
  float acc[8][4];
#pragma unroll
  for (int i = 0; i < 8; ++i)
#pragma unroll
    for (int j = 0; j < 4; ++j) acc[i][j] = 0.f;

  for (int k0 = 0; k0 < K; k0 += BK) {
    // A tile (transposed into LDS): 128x16 = 512 float4, 2 per thread
#pragma unroll
    for (int it = 0; it < 2; ++it) {
      int li = tid + it * 256;        // 0..511
      int row = li >> 2;              // 0..127
      int f4 = li & 3;                // which float4 in the 16-wide k slab
      const float4 v =
          *(const float4*)&A[(rowBase + row) * K + k0 + f4 * 4];
      As[f4 * 4 + 0][row] = v.x;
      As[f4 * 4 + 1][row] = v.y;
      As[f4 * 4 + 2][row] = v.z;
      As[f4 * 4 + 3][row] = v.w;
    }
    // B tile: 16x64, one float4 per thread (all-or-none column guard)
    {
      int kk = tid >> 4;
      int c4 = (tid & 15) * 4;
      int col = colBase + c4;
      float4 v = make_float4(0.f, 0.f, 0.f, 0.f);
      if (col + 3 < Nn) v = *(const float4*)&Bt[(size_t)(k0 + kk) * Nn + col];
      *(float4*)&Bs[kk][c4] = v;
    }
    __syncthreads();
#pragma unroll
    for (int kk = 0; kk < BK; ++kk) {
      float4 a0 = *(const float4*)&As[kk][ty * 8];
      float4 a1 = *(const float4*)&As[kk][ty * 8 + 4];
      float4 b  = *(const float4*)&Bs[kk][tx * 4];
      float av[8] = {a0.x, a0.y, a0.z, a0.w, a1.x, a1.y, a1.z, a1.w};
      float bv[4] = {b.x, b.y, b.z, b.w};
#pragma unroll
      for (int i = 0; i < 8; ++i)
#pragma unroll
        for (int j = 0; j < 4; ++j) acc[i][j] += av[i] * bv[j];
    }
    __syncthreads();
  }
  int col = colBase + tx * 4;
  if (col + 3 < Nn) {
    float4 bb = *(const float4*)&bias[col];
#pragma unroll
    for (int i = 0; i < 8; ++i) {
      long row = rowBase + ty * 8 + i;
      float4 o = make_float4(acc[i][0] + bb.x, acc[i][1] + bb.y,
                             acc[i][2] + bb.z, acc[i][3] + bb.w);
      *(float4*)&C[row * Nn + col] = o;
    }
  }
}

// ---------------------------------------------------------------------------
// Deformable bilinear sampling. One block per pixel; thread = (g, cg).
// samp[n,h,w,g,cg] = sum_k sum_taps wgt * mask * vproj[n, yi*W+xi, g, cg]
// ---------------------------------------------------------------------------
__global__ __launch_bounds__(256) void deform_sample(
    const float* __restrict__ vproj, const float* __restrict__ om,
    float* __restrict__ samp) {
  int p = blockIdx.x;           // global pixel 0..32767
  int n = p >> 12;
  int hw = p & 4095;
  int h = hw >> 6, w = hw & 63;
  int tid = threadIdx.x;
  int g = tid >> 6;             // 0..3

  __shared__ float s_px[36], s_py[36], s_mask[36];
  if (tid < 36) {
    int g2 = tid / 9, k = tid % 9;
    const float* o = om + (size_t)p * OMD;
    float ox = o[(g2 * 9 + k) * 2];
    float oy = o[(g2 * 9 + k) * 2 + 1];
    s_mask[tid] = o[72 + g2 * 9 + k];
    s_px[tid] = (float)w + (float)(k % 3 - 1) + ox;
    s_py[tid] = (float)h + (float)(k / 3 - 1) + oy;
  }
  __syncthreads();

  const float* vb = vproj + (size_t)(n << 12) * 256 + tid;  // tid == g*64+cg
  float acc = 0.f;
#pragma unroll
  for (int k = 0; k < 9; ++k) {
    float px = s_px[g * 9 + k], py = s_py[g * 9 + k], m = s_mask[g * 9 + k];
    float x0f = floorf(px), y0f = floorf(py);
    int x0 = (int)x0f, y0 = (int)y0f;
    float fx = px - x0f, fy = py - y0f;
    float w00 = (1.f - fx) * (1.f - fy) * m;
    float w01 = fx * (1.f - fy) * m;
    float w10 = (1.f - fx) * fy * m;
    float w11 = fx * fy * m;
    bool vx0 = (x0 >= 0) && (x0 <= 63);
    bool vx1 = (x0 + 1 >= 0) && (x0 + 1 <= 63);
    bool vy0 = (y0 >= 0) && (y0 <= 63);
    bool vy1 = (y0 + 1 >= 0) && (y0 + 1 <= 63);
    if (vy0 && vx0) acc += w00 * vb[(size_t)(y0 * 64 + x0) * 256];
    if (vy0 && vx1) acc += w01 * vb[(size_t)(y0 * 64 + x0 + 1) * 256];
    if (vy1 && vx0) acc += w10 * vb[(size_t)((y0 + 1) * 64 + x0) * 256];
    if (vy1 && vx1) acc += w11 * vb[(size_t)((y0 + 1) * 64 + x0 + 1) * 256];
  }
  samp[(size_t)p * 256 + tid] = acc;
}

// ---------------------------------------------------------------------------
extern "C" void kernel_launch(void* const* d_in, const int* in_sizes, int n_in,
                              void* d_out, int out_size, void* d_ws,
                              size_t ws_size, hipStream_t stream) {
  const float* x     = (const float*)d_in[0];
  // d_in[1]=shape_h, d_in[2]=shape_w (scalars, unused)
  const float* w_in  = (const float*)d_in[3];
  const float* b_in  = (const float*)d_in[4];
  const float* w_out = (const float*)d_in[5];
  const float* b_out = (const float*)d_in[6];
  const float* w_dw  = (const float*)d_in[7];
  const float* b_dw  = (const float*)d_in[8];
  const float* w_pw  = (const float*)d_in[9];
  const float* b_pw  = (const float*)d_in[10];
  float* out = (float*)d_out;
  float* ws  = (float*)d_ws;

  // Workspace layout (floats):
  float* vproj   = ws;                 // 8388608 (32 MB)
  float* dwbuf   = ws + 8388608;       // 8388608 (dw conv out, reused as samp)
  float* om      = ws + 16777216;      // 32768*112 = 3670016
  float* w_in_t  = ws + 20447232;      // 65536
  float* w_out_t = ws + 20512768;      // 65536
  float* w_pw_t  = ws + 20578304;      // 28672  (end: 20606976 floats ~82.5MB)

  transpose_weights<<<624, 256, 0, stream>>>(w_in, w_out, w_pw,
                                             w_in_t, w_out_t, w_pw_t);
  dwconv<<<M_ROWS, 256, 0, stream>>>(x, w_dw, b_dw, dwbuf);
  // om = dw @ w_pw.T + b_pw   (M=32768, N=112, K=256)
  gemm_bias<<<dim3(M_ROWS / 128, 2), 256, 0, stream>>>(dwbuf, w_pw_t, b_pw,
                                                       om, OMD, 256);
  // vproj = x @ w_in.T + b_in (M=32768, N=256, K=256)
  gemm_bias<<<dim3(M_ROWS / 128, 4), 256, 0, stream>>>(x, w_in_t, b_in,
                                                       vproj, 256, 256);
  deform_sample<<<M_ROWS, 256, 0, stream>>>(vproj, om, dwbuf /* samp */);
  // out = samp @ w_out.T + b_out (M=32768, N=256, K=256)
  gemm_bias<<<dim3(M_ROWS / 128, 4), 256, 0, stream>>>(dwbuf, w_out_t, b_out,
                                                       out, 256, 256);
}

// Round 2
// 247.188 us; speedup vs baseline: 1.4825x; 1.4825x over previous
//
#include <hip/hip_runtime.h>

// Problem constants (fixed by reference)
#define N_B   8
#define H_DIM 64
#define W_DIM 64
#define HW    4096
#define C_DIM 256
#define G_G   4
#define GD_D  64
#define OMD   112   // OM_DIM
#define M_ROWS (N_B * HW)   // 32768

// ---------------------------------------------------------------------------
// Weight transposes: w_in_t[k][c], w_out_t[k][c], w_pw_t[c][o]
// ---------------------------------------------------------------------------
__global__ __launch_bounds__(256) void transpose_weights(
    const float* __restrict__ w_in, const float* __restrict__ w_out,
    const float* __restrict__ w_pw, float* __restrict__ w_in_t,
    float* __restrict__ w_out_t, float* __restrict__ w_pw_t) {
  int idx = blockIdx.x * 256 + threadIdx.x;
  if (idx < 65536) {
    int k = idx >> 8, c = idx & 255;
    w_in_t[idx] = w_in[c * 256 + k];
  } else if (idx < 131072) {
    int i = idx - 65536;
    int k = i >> 8, c = i & 255;
    w_out_t[i] = w_out[c * 256 + k];
  } else if (idx < 131072 + 256 * OMD) {
    int i = idx - 131072;
    int c = i / OMD, o = i % OMD;
    w_pw_t[i] = w_pw[o * 256 + c];
  }
}

// ---------------------------------------------------------------------------
// Depthwise 3x3 conv (zero pad), NHWC, one thread per (pixel, channel)
// ---------------------------------------------------------------------------
__global__ __launch_bounds__(256) void dwconv(
    const float* __restrict__ x, const float* __restrict__ w_dw,
    const float* __restrict__ b_dw, float* __restrict__ dw) {
  int idx = blockIdx.x * 256 + threadIdx.x;   // (pixel, c), 8.4M total
  int c  = idx & 255;
  int pp = idx >> 8;                           // global pixel 0..32767
  int n  = pp >> 12;
  int hw = pp & 4095;
  int h = hw >> 6, w = hw & 63;
  float acc = b_dw[c];
#pragma unroll
  for (int ky = 0; ky < 3; ++ky) {
    int iy = h + ky - 1;
    if (iy < 0 || iy > 63) continue;
#pragma unroll
    for (int kx = 0; kx < 3; ++kx) {
      int ix = w + kx - 1;
      if (ix < 0 || ix > 63) continue;
      acc += x[((size_t)(n << 12) + iy * 64 + ix) * 256 + c]
           * w_dw[(ky * 3 + kx) * 256 + c];
    }
  }
  dw[(size_t)idx] = acc;
}

// ---------------------------------------------------------------------------
// fp32 register-tiled GEMM: C[M,Nn] = A[M,K] * Bt[K,Nn] + bias[Nn]
// BM=128, BN=64, BK=16, 256 threads, 8x4 acc per thread.
// ---------------------------------------------------------------------------
__global__ __launch_bounds__(256) void gemm_bias(
    const float* __restrict__ A, const float* __restrict__ Bt,
    const float* __restrict__ bias, float* __restrict__ C,
    int Nn, int K) {
  const int BM = 128, BK = 16;
  __shared__ __align__(16) float As[BK][BM];   // [kk][row]
  __shared__ __align__(16) float Bs[BK][64];   // [kk][col]
  int tid = threadIdx.x;
  long rowBase = (long)blockIdx.x * BM;
  int colBase = blockIdx.y * 64;
  int tx = tid & 15, ty = tid >> 4;            // cols tx*4, rows ty*8
  float acc[8][4];
#pragma unroll
  for (int i = 0; i < 8; ++i)
#pragma unroll
    for (int j = 0; j < 4; ++j) acc[i][j] = 0.f;

  for (int k0 = 0; k0 < K; k0 += BK) {
#pragma unroll
    for (int it = 0; it < 2; ++it) {
      int li = tid + it * 256;        // 0..511
      int row = li >> 2;              // 0..127
      int f4 = li & 3;
      const float4 v =
          *(const float4*)&A[(rowBase + row) * K + k0 + f4 * 4];
      As[f4 * 4 + 0][row] = v.x;
      As[f4 * 4 + 1][row] = v.y;
      As[f4 * 4 + 2][row] = v.z;
      As[f4 * 4 + 3][row] = v.w;
    }
    {
      int kk = tid >> 4;
      int c4 = (tid & 15) * 4;
      int col = colBase + c4;
      float4 v = make_float4(0.f, 0.f, 0.f, 0.f);
      if (col + 3 < Nn) v = *(const float4*)&Bt[(size_t)(k0 + kk) * Nn + col];
      *(float4*)&Bs[kk][c4] = v;
    }
    __syncthreads();
#pragma unroll
    for (int kk = 0; kk < BK; ++kk) {
      float4 a0 = *(const float4*)&As[kk][ty * 8];
      float4 a1 = *(const float4*)&As[kk][ty * 8 + 4];
      float4 b  = *(const float4*)&Bs[kk][tx * 4];
      float av[8] = {a0.x, a0.y, a0.z, a0.w, a1.x, a1.y, a1.z, a1.w};
      float bv[4] = {b.x, b.y, b.z, b.w};
#pragma unroll
      for (int i = 0; i < 8; ++i)
#pragma unroll
        for (int j = 0; j < 4; ++j) acc[i][j] += av[i] * bv[j];
    }
    __syncthreads();
  }
  int col = colBase + tx * 4;
  if (col + 3 < Nn) {
    float4 bb = *(const float4*)&bias[col];
#pragma unroll
    for (int i = 0; i < 8; ++i) {
      long row = rowBase + ty * 8 + i;
      float4 o = make_float4(acc[i][0] + bb.x, acc[i][1] + bb.y,
                             acc[i][2] + bb.z, acc[i][3] + bb.w);
      *(float4*)&C[row * Nn + col] = o;
    }
  }
}

// ---------------------------------------------------------------------------
// Deformable bilinear sampling, v2.
// Block = 256 threads = 4 waves; wave w handles pixel p0+w (one full pixel:
// lane l owns channels 4l..4l+3 as a float4; g = l>>4).
// Bilinear weights/corners precomputed once per (pix,g,k) into LDS.
// Grid = 8192 blocks, XCD-chunked swizzle (1024 blocks = one image per XCD).
// ---------------------------------------------------------------------------
__global__ __launch_bounds__(256) void deform_sample4(
    const float* __restrict__ vproj, const float* __restrict__ om,
    float* __restrict__ samp) {
  int bid = blockIdx.x;
  int swz = (bid & 7) * 1024 + (bid >> 3);   // 8192 % 8 == 0 -> bijective
  int p0 = swz * 4;

  int tid = threadIdx.x;
  int wave = tid >> 6, lane = tid & 63;

  __shared__ float s_w[4][36][4];   // w00,w01,w10,w11
  __shared__ int   s_xy[4][36][2];  // x0,y0
  if (tid < 144) {
    int pix = tid / 36;
    int gk = tid % 36;
    int k = gk % 9;
    int p = p0 + pix;
    int h = (p >> 6) & 63, w = p & 63;
    const float* o = om + (size_t)p * OMD;
    float ox = o[gk * 2], oy = o[gk * 2 + 1];
    float m = o[72 + gk];
    float px = (float)(w + (k % 3) - 1) + ox;
    float py = (float)(h + (k / 3) - 1) + oy;
    float x0f = floorf(px), y0f = floorf(py);
    float fx = px - x0f, fy = py - y0f;
    s_w[pix][gk][0] = (1.f - fx) * (1.f - fy) * m;
    s_w[pix][gk][1] = fx * (1.f - fy) * m;
    s_w[pix][gk][2] = (1.f - fx) * fy * m;
    s_w[pix][gk][3] = fx * fy * m;
    s_xy[pix][gk][0] = (int)x0f;
    s_xy[pix][gk][1] = (int)y0f;
  }
  __syncthreads();

  int p = p0 + wave;
  int n = p >> 12;
  int g = lane >> 4;
  const float* vbase = vproj + (((size_t)n << 12)) * 256 + lane * 4;

  float4 acc = make_float4(0.f, 0.f, 0.f, 0.f);
#pragma unroll
  for (int k = 0; k < 9; ++k) {
    int gk = g * 9 + k;
    float w00 = s_w[wave][gk][0];
    float w01 = s_w[wave][gk][1];
    float w10 = s_w[wave][gk][2];
    float w11 = s_w[wave][gk][3];
    int x0 = s_xy[wave][gk][0];
    int y0 = s_xy[wave][gk][1];
    bool vx0 = (unsigned)x0 < 64u;
    bool vx1 = (unsigned)(x0 + 1) < 64u;
    bool vy0 = (unsigned)y0 < 64u;
    bool vy1 = (unsigned)(y0 + 1) < 64u;
    if (vy0 && vx0) {
      float4 v = *(const float4*)&vbase[(size_t)(y0 * 64 + x0) * 256];
      acc.x += w00 * v.x; acc.y += w00 * v.y;
      acc.z += w00 * v.z; acc.w += w00 * v.w;
    }
    if (vy0 && vx1) {
      float4 v = *(const float4*)&vbase[(size_t)(y0 * 64 + x0 + 1) * 256];
      acc.x += w01 * v.x; acc.y += w01 * v.y;
      acc.z += w01 * v.z; acc.w += w01 * v.w;
    }
    if (vy1 && vx0) {
      float4 v = *(const float4*)&vbase[(size_t)((y0 + 1) * 64 + x0) * 256];
      acc.x += w10 * v.x; acc.y += w10 * v.y;
      acc.z += w10 * v.z; acc.w += w10 * v.w;
    }
    if (vy1 && vx1) {
      float4 v = *(const float4*)&vbase[(size_t)((y0 + 1) * 64 + x0 + 1) * 256];
      acc.x += w11 * v.x; acc.y += w11 * v.y;
      acc.z += w11 * v.z; acc.w += w11 * v.w;
    }
  }
  *(float4*)&samp[(size_t)p * 256 + lane * 4] = acc;
}

// ---------------------------------------------------------------------------
extern "C" void kernel_launch(void* const* d_in, const int* in_sizes, int n_in,
                              void* d_out, int out_size, void* d_ws,
                              size_t ws_size, hipStream_t stream) {
  const float* x     = (const float*)d_in[0];
  const float* w_in  = (const float*)d_in[3];
  const float* b_in  = (const float*)d_in[4];
  const float* w_out = (const float*)d_in[5];
  const float* b_out = (const float*)d_in[6];
  const float* w_dw  = (const float*)d_in[7];
  const float* b_dw  = (const float*)d_in[8];
  const float* w_pw  = (const float*)d_in[9];
  const float* b_pw  = (const float*)d_in[10];
  float* out = (float*)d_out;
  float* ws  = (float*)d_ws;

  float* vproj   = ws;                 // 8388608 floats (32 MB)
  float* dwbuf   = ws + 8388608;       // 8388608 (dw conv out, reused as samp)
  float* om      = ws + 16777216;      // 32768*112 = 3670016
  float* w_in_t  = ws + 20447232;      // 65536
  float* w_out_t = ws + 20512768;      // 65536
  float* w_pw_t  = ws + 20578304;      // 28672

  transpose_weights<<<624, 256, 0, stream>>>(w_in, w_out, w_pw,
                                             w_in_t, w_out_t, w_pw_t);
  dwconv<<<M_ROWS, 256, 0, stream>>>(x, w_dw, b_dw, dwbuf);
  gemm_bias<<<dim3(M_ROWS / 128, 2), 256, 0, stream>>>(dwbuf, w_pw_t, b_pw,
                                                       om, OMD, 256);
  gemm_bias<<<dim3(M_ROWS / 128, 4), 256, 0, stream>>>(x, w_in_t, b_in,
                                                       vproj, 256, 256);
  deform_sample4<<<M_ROWS / 4, 256, 0, stream>>>(vproj, om, dwbuf /* samp */);
  gemm_bias<<<dim3(M_ROWS / 128, 4), 256, 0, stream>>>(dwbuf, w_out_t, b_out,
                                                       out, 256, 256);
}

// Round 3
// 116.589 us; speedup vs baseline: 3.1431x; 2.1202x over previous
//
#include <hip/hip_runtime.h>

// Problem constants (fixed by reference)
#define HW     4096
#define M_ROWS 32768        // N*H*W
#define OMD    112
#define OMP    128          // padded OM dim (stride)

typedef __attribute__((ext_vector_type(8))) short short8;
typedef __attribute__((ext_vector_type(4))) float f32x4;

__device__ inline unsigned short f2bf(float f) {
  union { float f; unsigned int u; } v; v.f = f;
  unsigned int u = v.u;
  u += 0x7fffu + ((u >> 16) & 1u);      // RNE
  return (unsigned short)(u >> 16);
}
__device__ inline float bf2f(unsigned short h) {
  union { unsigned int u; float f; } v; v.u = ((unsigned int)h) << 16;
  return v.f;
}

// ---------------------------------------------------------------------------
// x fp32 -> bf16, 8 elems/thread
// ---------------------------------------------------------------------------
__global__ __launch_bounds__(256) void convert_x(
    const float* __restrict__ x, unsigned short* __restrict__ xb) {
  size_t i = ((size_t)blockIdx.x * 256 + threadIdx.x) * 8;
  float4 a = *(const float4*)&x[i];
  float4 b = *(const float4*)&x[i + 4];
  union { unsigned short s[8]; short8 v; } o;
  o.s[0] = f2bf(a.x); o.s[1] = f2bf(a.y); o.s[2] = f2bf(a.z); o.s[3] = f2bf(a.w);
  o.s[4] = f2bf(b.x); o.s[5] = f2bf(b.y); o.s[6] = f2bf(b.z); o.s[7] = f2bf(b.w);
  *(short8*)&xb[i] = o.v;
}

// ---------------------------------------------------------------------------
// Weights fp32 -> bf16 (layouts kept [N][K]); w_pw/b_pw zero-padded to 128 rows
// ---------------------------------------------------------------------------
__global__ __launch_bounds__(256) void convert_weights(
    const float* __restrict__ w_in, const float* __restrict__ w_out,
    const float* __restrict__ w_pw, const float* __restrict__ b_pw,
    unsigned short* __restrict__ wi_b, unsigned short* __restrict__ wo_b,
    unsigned short* __restrict__ wp_b, float* __restrict__ bpw_pad) {
  int idx = blockIdx.x * 256 + threadIdx.x;
  if (idx < 65536) {
    wi_b[idx] = f2bf(w_in[idx]);
  } else if (idx < 131072) {
    int i = idx - 65536;
    wo_b[i] = f2bf(w_out[i]);
  } else if (idx < 131072 + OMP * 256) {
    int i = idx - 131072;
    int o = i >> 8;
    wp_b[i] = (o < OMD) ? f2bf(w_pw[i]) : (unsigned short)0;
  } else if (idx < 131072 + OMP * 256 + OMP) {
    int i = idx - (131072 + OMP * 256);
    bpw_pad[i] = (i < OMD) ? b_pw[i] : 0.f;
  }
}

// ---------------------------------------------------------------------------
// Depthwise 3x3 (zero pad), bf16 in/out, 4 channels per thread
// ---------------------------------------------------------------------------
__global__ __launch_bounds__(256) void dwconv_b(
    const unsigned short* __restrict__ xb, const float* __restrict__ w_dw,
    const float* __restrict__ b_dw, unsigned short* __restrict__ dwb) {
  int idx = blockIdx.x * 256 + threadIdx.x;   // (pixel, c/4): 32768*64
  int c4 = (idx & 63) * 4;
  int pp = idx >> 6;
  int n = pp >> 12;
  int hw = pp & 4095;
  int h = hw >> 6, w = hw & 63;
  float4 bb = *(const float4*)&b_dw[c4];
  float a0 = bb.x, a1 = bb.y, a2 = bb.z, a3 = bb.w;
#pragma unroll
  for (int ky = 0; ky < 3; ++ky) {
    int iy = h + ky - 1;
    if (iy < 0 || iy > 63) continue;
#pragma unroll
    for (int kx = 0; kx < 3; ++kx) {
      int ix = w + kx - 1;
      if (ix < 0 || ix > 63) continue;
      ushort4 xv = *(const ushort4*)&xb[((size_t)(n << 12) + iy * 64 + ix) * 256 + c4];
      float4 wv = *(const float4*)&w_dw[(ky * 3 + kx) * 256 + c4];
      a0 += bf2f(xv.x) * wv.x;
      a1 += bf2f(xv.y) * wv.y;
      a2 += bf2f(xv.z) * wv.z;
      a3 += bf2f(xv.w) * wv.w;
    }
  }
  ushort4 o;
  o.x = f2bf(a0); o.y = f2bf(a1); o.z = f2bf(a2); o.w = f2bf(a3);
  *(ushort4*)&dwb[(size_t)pp * 256 + c4] = o;
}

// ---------------------------------------------------------------------------
// bf16 MFMA GEMM: C[M,NN] = A[M,256] @ W[NN_rows,256]^T + bias
// m97 structure: 128x128 tile, BK=32, 4 waves (2x2), 4x4 16x16x32 frags/wave,
// global_load_lds width-16 staging, linear LDS, 2 barriers/K-step.
// Grid: 1-D (M/128)*(NN/128), XCD-chunked swizzle.
// ---------------------------------------------------------------------------
template <int NN, bool OUTBF>
__global__ __launch_bounds__(256) void gemm_mfma(
    const unsigned short* __restrict__ A, const unsigned short* __restrict__ W,
    const float* __restrict__ bias, void* __restrict__ Cout) {
  constexpr int NB = NN / 128;
  __shared__ __align__(16) unsigned short As[128 * 32];  // 8 KB
  __shared__ __align__(16) unsigned short Bs[128 * 32];  // 8 KB
  int tid = threadIdx.x;
  int wave = tid >> 6, lane = tid & 63;
  int wr = wave >> 1, wc = wave & 1;

  constexpr int TOTAL = 256 * NB;           // grid size (512 or 256), %8==0
  int bid = blockIdx.x;
  int swz = (bid & 7) * (TOTAL >> 3) + (bid >> 3);
  int mb, nbk;
  if (NB == 2) { mb = swz >> 1; nbk = swz & 1; } else { mb = swz; nbk = 0; }
  size_t rowB = (size_t)mb * 128;
  int colB = nbk * 128;

  f32x4 acc[4][4];
#pragma unroll
  for (int m = 0; m < 4; ++m)
#pragma unroll
    for (int n = 0; n < 4; ++n) acc[m][n] = (f32x4)(0.f);

  int arow = lane >> 2;          // row within 16-row staging group
  int acol = (lane & 3) * 8;     // bf16 index within 32-wide k slab

  for (int k0 = 0; k0 < 256; k0 += 32) {
#pragma unroll
    for (int jj = 0; jj < 2; ++jj) {
      int j = wave * 2 + jj;     // staging instruction 0..7 (16 rows each)
      const unsigned short* ga = A + (rowB + 16 * j + arow) * 256 + k0 + acol;
      __builtin_amdgcn_global_load_lds(
          (const __attribute__((address_space(1))) unsigned int*)ga,
          (__attribute__((address_space(3))) unsigned int*)(As + j * 512),
          16, 0, 0);
      const unsigned short* gb =
          W + ((size_t)(colB + 16 * j + arow)) * 256 + k0 + acol;
      __builtin_amdgcn_global_load_lds(
          (const __attribute__((address_space(1))) unsigned int*)gb,
          (__attribute__((address_space(3))) unsigned int*)(Bs + j * 512),
          16, 0, 0);
    }
    __syncthreads();   // drains vmcnt (compiler emits waitcnt before barrier)

    short8 aF[4], bF[4];
#pragma unroll
    for (int m = 0; m < 4; ++m)
      aF[m] = *(const short8*)&As[(wr * 64 + m * 16 + (lane & 15)) * 32 +
                                  (lane >> 4) * 8];
#pragma unroll
    for (int n = 0; n < 4; ++n)
      bF[n] = *(const short8*)&Bs[(wc * 64 + n * 16 + (lane & 15)) * 32 +
                                  (lane >> 4) * 8];
#pragma unroll
    for (int m = 0; m < 4; ++m)
#pragma unroll
      for (int n = 0; n < 4; ++n)
        acc[m][n] = __builtin_amdgcn_mfma_f32_16x16x32_bf16(
            aF[m], bF[n], acc[m][n], 0, 0, 0);
    __syncthreads();
  }

  // Epilogue: C/D layout col=lane&15, row=(lane>>4)*4+j  [m89-verified]
#pragma unroll
  for (int n = 0; n < 4; ++n) {
    int col = colB + wc * 64 + n * 16 + (lane & 15);
    float bv = bias[col];
#pragma unroll
    for (int m = 0; m < 4; ++m) {
#pragma unroll
      for (int j = 0; j < 4; ++j) {
        size_t row = rowB + wr * 64 + m * 16 + (lane >> 4) * 4 + j;
        float v = acc[m][n][j] + bv;
        if (OUTBF)
          ((unsigned short*)Cout)[row * NN + col] = f2bf(v);
        else
          ((float*)Cout)[row * NN + col] = v;
      }
    }
  }
}

// ---------------------------------------------------------------------------
// Deformable bilinear sampling (bf16 vproj -> bf16 samp).
// Block = 4 waves = 4 pixels; lane owns 4 channels (ushort4 loads).
// om is fp32 with row stride OMP=128. XCD-chunked block swizzle.
// ---------------------------------------------------------------------------
__global__ __launch_bounds__(256) void deform_sample_b(
    const unsigned short* __restrict__ vproj, const float* __restrict__ om,
    unsigned short* __restrict__ samp) {
  int bid = blockIdx.x;
  int swz = (bid & 7) * 1024 + (bid >> 3);   // 8192 % 8 == 0 -> bijective
  int p0 = swz * 4;

  int tid = threadIdx.x;
  int wave = tid >> 6, lane = tid & 63;

  __shared__ float s_w[4][36][4];   // w00,w01,w10,w11
  __shared__ int   s_xy[4][36][2];  // x0,y0
  if (tid < 144) {
    int pix = tid / 36;
    int gk = tid % 36;
    int k = gk % 9;
    int p = p0 + pix;
    int h = (p >> 6) & 63, w = p & 63;
    const float* o = om + (size_t)p * OMP;
    float ox = o[gk * 2], oy = o[gk * 2 + 1];
    float m = o[72 + gk];
    float px = (float)(w + (k % 3) - 1) + ox;
    float py = (float)(h + (k / 3) - 1) + oy;
    float x0f = floorf(px), y0f = floorf(py);
    float fx = px - x0f, fy = py - y0f;
    s_w[pix][gk][0] = (1.f - fx) * (1.f - fy) * m;
    s_w[pix][gk][1] = fx * (1.f - fy) * m;
    s_w[pix][gk][2] = (1.f - fx) * fy * m;
    s_w[pix][gk][3] = fx * fy * m;
    s_xy[pix][gk][0] = (int)x0f;
    s_xy[pix][gk][1] = (int)y0f;
  }
  __syncthreads();

  int p = p0 + wave;
  int n = p >> 12;
  int g = lane >> 4;
  const unsigned short* vb = vproj + (((size_t)n << 12)) * 256 + lane * 4;

  float a0 = 0.f, a1 = 0.f, a2 = 0.f, a3 = 0.f;
#pragma unroll
  for (int k = 0; k < 9; ++k) {
    int gk = g * 9 + k;
    float w00 = s_w[wave][gk][0];
    float w01 = s_w[wave][gk][1];
    float w10 = s_w[wave][gk][2];
    float w11 = s_w[wave][gk][3];
    int x0 = s_xy[wave][gk][0];
    int y0 = s_xy[wave][gk][1];
    bool vx0 = (unsigned)x0 < 64u;
    bool vx1 = (unsigned)(x0 + 1) < 64u;
    bool vy0 = (unsigned)y0 < 64u;
    bool vy1 = (unsigned)(y0 + 1) < 64u;
    if (vy0 && vx0) {
      ushort4 v = *(const ushort4*)&vb[(size_t)(y0 * 64 + x0) * 256];
      a0 += w00 * bf2f(v.x); a1 += w00 * bf2f(v.y);
      a2 += w00 * bf2f(v.z); a3 += w00 * bf2f(v.w);
    }
    if (vy0 && vx1) {
      ushort4 v = *(const ushort4*)&vb[(size_t)(y0 * 64 + x0 + 1) * 256];
      a0 += w01 * bf2f(v.x); a1 += w01 * bf2f(v.y);
      a2 += w01 * bf2f(v.z); a3 += w01 * bf2f(v.w);
    }
    if (vy1 && vx0) {
      ushort4 v = *(const ushort4*)&vb[(size_t)((y0 + 1) * 64 + x0) * 256];
      a0 += w10 * bf2f(v.x); a1 += w10 * bf2f(v.y);
      a2 += w10 * bf2f(v.z); a3 += w10 * bf2f(v.w);
    }
    if (vy1 && vx1) {
      ushort4 v = *(const ushort4*)&vb[(size_t)((y0 + 1) * 64 + x0 + 1) * 256];
      a0 += w11 * bf2f(v.x); a1 += w11 * bf2f(v.y);
      a2 += w11 * bf2f(v.z); a3 += w11 * bf2f(v.w);
    }
  }
  ushort4 o;
  o.x = f2bf(a0); o.y = f2bf(a1); o.z = f2bf(a2); o.w = f2bf(a3);
  *(ushort4*)&samp[(size_t)p * 256 + lane * 4] = o;
}

// ---------------------------------------------------------------------------
extern "C" void kernel_launch(void* const* d_in, const int* in_sizes, int n_in,
                              void* d_out, int out_size, void* d_ws,
                              size_t ws_size, hipStream_t stream) {
  const float* x     = (const float*)d_in[0];
  const float* w_in  = (const float*)d_in[3];
  const float* b_in  = (const float*)d_in[4];
  const float* w_out = (const float*)d_in[5];
  const float* b_out = (const float*)d_in[6];
  const float* w_dw  = (const float*)d_in[7];
  const float* b_dw  = (const float*)d_in[8];
  const float* w_pw  = (const float*)d_in[9];
  const float* b_pw  = (const float*)d_in[10];
  float* out = (float*)d_out;
  char* ws = (char*)d_ws;

  // Workspace layout (bytes, 16-aligned):
  unsigned short* xb    = (unsigned short*)(ws);                  // 16 MB
  unsigned short* dwb   = (unsigned short*)(ws + (16u << 20));    // 16 MB (dw, reused as samp)
  unsigned short* vproj = (unsigned short*)(ws + (32u << 20));    // 16 MB
  float*          om    = (float*)(ws + (48u << 20));             // 16 MB (stride 128)
  unsigned short* wi_b  = (unsigned short*)(ws + (64u << 20));    // 128 KB
  unsigned short* wo_b  = (unsigned short*)(ws + (64u << 20) + (128u << 10));
  unsigned short* wp_b  = (unsigned short*)(ws + (64u << 20) + (256u << 10)); // 64 KB
  float*          bpw   = (float*)(ws + (64u << 20) + (320u << 10));          // 512 B

  convert_x<<<4096, 256, 0, stream>>>(x, xb);
  convert_weights<<<642, 256, 0, stream>>>(w_in, w_out, w_pw, b_pw,
                                           wi_b, wo_b, wp_b, bpw);
  dwconv_b<<<8192, 256, 0, stream>>>(xb, w_dw, b_dw, dwb);
  // om = dw @ w_pw^T + b_pw   (N padded to 128)
  gemm_mfma<128, false><<<256, 256, 0, stream>>>(dwb, wp_b, bpw, om);
  // vproj = x @ w_in^T + b_in  (bf16 out)
  gemm_mfma<256, true><<<512, 256, 0, stream>>>(xb, wi_b, b_in, vproj);
  deform_sample_b<<<8192, 256, 0, stream>>>(vproj, om, dwb /* samp */);
  // out = samp @ w_out^T + b_out (fp32 out)
  gemm_mfma<256, false><<<512, 256, 0, stream>>>(dwb, wo_b, b_out, out);
}

// Round 4
// 94.524 us; speedup vs baseline: 3.8768x; 1.2334x over previous
//
#include <hip/hip_runtime.h>

// Problem constants (fixed by reference)
#define HW     4096
#define M_ROWS 32768        // N*H*W
#define OMD    112
#define OMP    128          // padded OM dim (stride)

typedef __attribute__((ext_vector_type(8))) short short8;
typedef __attribute__((ext_vector_type(4))) float f32x4;

__device__ inline unsigned short f2bf(float f) {
  union { float f; unsigned int u; } v; v.f = f;
  unsigned int u = v.u;
  u += 0x7fffu + ((u >> 16) & 1u);      // RNE
  return (unsigned short)(u >> 16);
}
__device__ inline float bf2f(unsigned short h) {
  union { unsigned int u; float f; } v; v.u = ((unsigned int)h) << 16;
  return v.f;
}

// ---------------------------------------------------------------------------
// x fp32 -> bf16, 8 elems/thread
// ---------------------------------------------------------------------------
__global__ __launch_bounds__(256) void convert_x(
    const float* __restrict__ x, unsigned short* __restrict__ xb) {
  size_t i = ((size_t)blockIdx.x * 256 + threadIdx.x) * 8;
  float4 a = *(const float4*)&x[i];
  float4 b = *(const float4*)&x[i + 4];
  union { unsigned short s[8]; short8 v; } o;
  o.s[0] = f2bf(a.x); o.s[1] = f2bf(a.y); o.s[2] = f2bf(a.z); o.s[3] = f2bf(a.w);
  o.s[4] = f2bf(b.x); o.s[5] = f2bf(b.y); o.s[6] = f2bf(b.z); o.s[7] = f2bf(b.w);
  *(short8*)&xb[i] = o.v;
}

// ---------------------------------------------------------------------------
// Weights fp32 -> bf16 (layouts kept [N][K]); w_pw/b_pw zero-padded to 128 rows
// ---------------------------------------------------------------------------
__global__ __launch_bounds__(256) void convert_weights(
    const float* __restrict__ w_in, const float* __restrict__ w_out,
    const float* __restrict__ w_pw, const float* __restrict__ b_pw,
    unsigned short* __restrict__ wi_b, unsigned short* __restrict__ wo_b,
    unsigned short* __restrict__ wp_b, float* __restrict__ bpw_pad) {
  int idx = blockIdx.x * 256 + threadIdx.x;
  if (idx < 65536) {
    wi_b[idx] = f2bf(w_in[idx]);
  } else if (idx < 131072) {
    int i = idx - 65536;
    wo_b[i] = f2bf(w_out[i]);
  } else if (idx < 131072 + OMP * 256) {
    int i = idx - 131072;
    int o = i >> 8;
    wp_b[i] = (o < OMD) ? f2bf(w_pw[i]) : (unsigned short)0;
  } else if (idx < 131072 + OMP * 256 + OMP) {
    int i = idx - (131072 + OMP * 256);
    bpw_pad[i] = (i < OMD) ? b_pw[i] : 0.f;
  }
}

// ---------------------------------------------------------------------------
// Depthwise 3x3 (zero pad), bf16 in/out, 4 channels per thread
// ---------------------------------------------------------------------------
__global__ __launch_bounds__(256) void dwconv_b(
    const unsigned short* __restrict__ xb, const float* __restrict__ w_dw,
    const float* __restrict__ b_dw, unsigned short* __restrict__ dwb) {
  int idx = blockIdx.x * 256 + threadIdx.x;   // (pixel, c/4): 32768*64
  int c4 = (idx & 63) * 4;
  int pp = idx >> 6;
  int n = pp >> 12;
  int hw = pp & 4095;
  int h = hw >> 6, w = hw & 63;
  float4 bb = *(const float4*)&b_dw[c4];
  float a0 = bb.x, a1 = bb.y, a2 = bb.z, a3 = bb.w;
#pragma unroll
  for (int ky = 0; ky < 3; ++ky) {
    int iy = h + ky - 1;
    if (iy < 0 || iy > 63) continue;
#pragma unroll
    for (int kx = 0; kx < 3; ++kx) {
      int ix = w + kx - 1;
      if (ix < 0 || ix > 63) continue;
      ushort4 xv = *(const ushort4*)&xb[((size_t)(n << 12) + iy * 64 + ix) * 256 + c4];
      float4 wv = *(const float4*)&w_dw[(ky * 3 + kx) * 256 + c4];
      a0 += bf2f(xv.x) * wv.x;
      a1 += bf2f(xv.y) * wv.y;
      a2 += bf2f(xv.z) * wv.z;
      a3 += bf2f(xv.w) * wv.w;
    }
  }
  ushort4 o;
  o.x = f2bf(a0); o.y = f2bf(a1); o.z = f2bf(a2); o.w = f2bf(a3);
  *(ushort4*)&dwb[(size_t)pp * 256 + c4] = o;
}

// ---------------------------------------------------------------------------
// bf16 MFMA GEMM: C[M,NN] = A[M,256] @ W[NN_rows,256]^T + bias
// m97 structure: 128x128 tile, BK=32, 4 waves (2x2), 4x4 16x16x32 frags/wave,
// global_load_lds width-16 staging, linear LDS, 2 barriers/K-step.
// ---------------------------------------------------------------------------
template <int NN, bool OUTBF>
__global__ __launch_bounds__(256) void gemm_mfma(
    const unsigned short* __restrict__ A, const unsigned short* __restrict__ W,
    const float* __restrict__ bias, void* __restrict__ Cout) {
  constexpr int NB = NN / 128;
  __shared__ __align__(16) unsigned short As[128 * 32];  // 8 KB
  __shared__ __align__(16) unsigned short Bs[128 * 32];  // 8 KB
  int tid = threadIdx.x;
  int wave = tid >> 6, lane = tid & 63;
  int wr = wave >> 1, wc = wave & 1;

  constexpr int TOTAL = 256 * NB;           // grid size (512 or 256), %8==0
  int bid = blockIdx.x;
  int swz = (bid & 7) * (TOTAL >> 3) + (bid >> 3);
  int mb, nbk;
  if (NB == 2) { mb = swz >> 1; nbk = swz & 1; } else { mb = swz; nbk = 0; }
  size_t rowB = (size_t)mb * 128;
  int colB = nbk * 128;

  f32x4 acc[4][4];
#pragma unroll
  for (int m = 0; m < 4; ++m)
#pragma unroll
    for (int n = 0; n < 4; ++n) acc[m][n] = (f32x4)(0.f);

  int arow = lane >> 2;          // row within 16-row staging group
  int acol = (lane & 3) * 8;     // bf16 index within 32-wide k slab

  for (int k0 = 0; k0 < 256; k0 += 32) {
#pragma unroll
    for (int jj = 0; jj < 2; ++jj) {
      int j = wave * 2 + jj;     // staging instruction 0..7 (16 rows each)
      const unsigned short* ga = A + (rowB + 16 * j + arow) * 256 + k0 + acol;
      __builtin_amdgcn_global_load_lds(
          (const __attribute__((address_space(1))) unsigned int*)ga,
          (__attribute__((address_space(3))) unsigned int*)(As + j * 512),
          16, 0, 0);
      const unsigned short* gb =
          W + ((size_t)(colB + 16 * j + arow)) * 256 + k0 + acol;
      __builtin_amdgcn_global_load_lds(
          (const __attribute__((address_space(1))) unsigned int*)gb,
          (__attribute__((address_space(3))) unsigned int*)(Bs + j * 512),
          16, 0, 0);
    }
    __syncthreads();

    short8 aF[4], bF[4];
#pragma unroll
    for (int m = 0; m < 4; ++m)
      aF[m] = *(const short8*)&As[(wr * 64 + m * 16 + (lane & 15)) * 32 +
                                  (lane >> 4) * 8];
#pragma unroll
    for (int n = 0; n < 4; ++n)
      bF[n] = *(const short8*)&Bs[(wc * 64 + n * 16 + (lane & 15)) * 32 +
                                  (lane >> 4) * 8];
#pragma unroll
    for (int m = 0; m < 4; ++m)
#pragma unroll
      for (int n = 0; n < 4; ++n)
        acc[m][n] = __builtin_amdgcn_mfma_f32_16x16x32_bf16(
            aF[m], bF[n], acc[m][n], 0, 0, 0);
    __syncthreads();
  }

#pragma unroll
  for (int n = 0; n < 4; ++n) {
    int col = colB + wc * 64 + n * 16 + (lane & 15);
    float bv = bias[col];
#pragma unroll
    for (int m = 0; m < 4; ++m) {
#pragma unroll
      for (int j = 0; j < 4; ++j) {
        size_t row = rowB + wr * 64 + m * 16 + (lane >> 4) * 4 + j;
        float v = acc[m][n][j] + bv;
        if (OUTBF)
          ((unsigned short*)Cout)[row * NN + col] = f2bf(v);
        else
          ((float*)Cout)[row * NN + col] = v;
      }
    }
  }
}

// ---------------------------------------------------------------------------
// Deformable bilinear sampling, v3: branchless clamped gathers.
// Block = 256 threads = 4 waves = 8 pixels (2 px/wave; lane owns 8 channels).
// Precompute per (pixel, g, k): 4 validity-zeroed bilinear weights + 4 CLAMPED
// corner byte-offsets into LDS. Inner loop: 2 ds_read_b128 + 4 unconditional
// 16B gathers (SGPR image base + 32-bit voffset) + cvt/fma.
// Grid = 4096 blocks, XCD-chunked swizzle (512 blocks = one image per XCD).
// ---------------------------------------------------------------------------
__global__ __launch_bounds__(256) void deform_sample_b3(
    const unsigned short* __restrict__ vproj, const float* __restrict__ om,
    unsigned short* __restrict__ samp) {
  int bid = blockIdx.x;
  int swz = (bid & 7) * 512 + (bid >> 3);   // 4096 % 8 == 0 -> bijective
  int p0 = swz * 8;                          // 8 consecutive pixels, one image

  int tid = threadIdx.x;

  __shared__ __align__(16) float s_w[8][36][4];  // w00,w01,w10,w11 (zeroed invalid)
  __shared__ __align__(16) int   s_o[8][36][4];  // clamped corner byte offsets

  for (int it = tid; it < 288; it += 256) {
    int pix = it / 36, gk = it % 36;
    int k = gk % 9;
    int p = p0 + pix;
    int h = (p >> 6) & 63, w = p & 63;
    const float* o = om + (size_t)p * OMP;
    float ox = o[gk * 2], oy = o[gk * 2 + 1];
    float m = o[72 + gk];
    float px = (float)(w + (k % 3) - 1) + ox;
    float py = (float)(h + (k / 3) - 1) + oy;
    float x0f = floorf(px), y0f = floorf(py);
    int x0 = (int)x0f, y0 = (int)y0f;
    float fx = px - x0f, fy = py - y0f;
    bool vx0 = (unsigned)x0 < 64u;
    bool vx1 = (unsigned)(x0 + 1) < 64u;
    bool vy0 = (unsigned)y0 < 64u;
    bool vy1 = (unsigned)(y0 + 1) < 64u;
    s_w[pix][gk][0] = (vy0 && vx0) ? (1.f - fx) * (1.f - fy) * m : 0.f;
    s_w[pix][gk][1] = (vy0 && vx1) ? fx * (1.f - fy) * m : 0.f;
    s_w[pix][gk][2] = (vy1 && vx0) ? (1.f - fx) * fy * m : 0.f;
    s_w[pix][gk][3] = (vy1 && vx1) ? fx * fy * m : 0.f;
    int x0c = min(max(x0, 0), 63), x1c = min(max(x0 + 1, 0), 63);
    int y0c = min(max(y0, 0), 63), y1c = min(max(y0 + 1, 0), 63);
    s_o[pix][gk][0] = (y0c * 64 + x0c) * 512;   // bytes (256 ch * 2B)
    s_o[pix][gk][1] = (y0c * 64 + x1c) * 512;
    s_o[pix][gk][2] = (y1c * 64 + x0c) * 512;
    s_o[pix][gk][3] = (y1c * 64 + x1c) * 512;
  }
  __syncthreads();

  int wave = tid >> 6, lane = tid & 63;
  int pix2 = lane >> 5, sub = lane & 31, g = sub >> 3;
  int pixb = wave * 2 + pix2;               // pixel index within block, 0..7
  int p = p0 + pixb;
  int n = p0 >> 12;                          // uniform over block
  const char* vb = (const char*)(vproj + (((size_t)n << 12)) * 256);
  int choff = sub * 16;                      // channel byte offset (8 ch)

  float acc[8];
#pragma unroll
  for (int j = 0; j < 8; ++j) acc[j] = 0.f;

#pragma unroll
  for (int k = 0; k < 9; ++k) {
    int gk = g * 9 + k;
    float4 wv = *(const float4*)s_w[pixb][gk];
    int4 ov = *(const int4*)s_o[pixb][gk];
#pragma unroll
    for (int c = 0; c < 4; ++c) {
      int off = (c == 0) ? ov.x : (c == 1) ? ov.y : (c == 2) ? ov.z : ov.w;
      float wgt = (c == 0) ? wv.x : (c == 1) ? wv.y : (c == 2) ? wv.z : wv.w;
      short8 v = *(const short8*)(vb + off + choff);
#pragma unroll
      for (int j = 0; j < 8; ++j)
        acc[j] += wgt * bf2f((unsigned short)v[j]);
    }
  }

  union { unsigned short s[8]; short8 v8; } o;
#pragma unroll
  for (int j = 0; j < 8; ++j) o.s[j] = f2bf(acc[j]);
  *(short8*)&samp[(size_t)p * 256 + sub * 8] = o.v8;
}

// ---------------------------------------------------------------------------
extern "C" void kernel_launch(void* const* d_in, const int* in_sizes, int n_in,
                              void* d_out, int out_size, void* d_ws,
                              size_t ws_size, hipStream_t stream) {
  const float* x     = (const float*)d_in[0];
  const float* w_in  = (const float*)d_in[3];
  const float* b_in  = (const float*)d_in[4];
  const float* w_out = (const float*)d_in[5];
  const float* b_out = (const float*)d_in[6];
  const float* w_dw  = (const float*)d_in[7];
  const float* b_dw  = (const float*)d_in[8];
  const float* w_pw  = (const float*)d_in[9];
  const float* b_pw  = (const float*)d_in[10];
  float* out = (float*)d_out;
  char* ws = (char*)d_ws;

  unsigned short* xb    = (unsigned short*)(ws);                  // 16 MB
  unsigned short* dwb   = (unsigned short*)(ws + (16u << 20));    // 16 MB (dw, reused as samp)
  unsigned short* vproj = (unsigned short*)(ws + (32u << 20));    // 16 MB
  float*          om    = (float*)(ws + (48u << 20));             // 16 MB (stride 128)
  unsigned short* wi_b  = (unsigned short*)(ws + (64u << 20));    // 128 KB
  unsigned short* wo_b  = (unsigned short*)(ws + (64u << 20) + (128u << 10));
  unsigned short* wp_b  = (unsigned short*)(ws + (64u << 20) + (256u << 10)); // 64 KB
  float*          bpw   = (float*)(ws + (64u << 20) + (320u << 10));          // 512 B

  convert_x<<<4096, 256, 0, stream>>>(x, xb);
  convert_weights<<<642, 256, 0, stream>>>(w_in, w_out, w_pw, b_pw,
                                           wi_b, wo_b, wp_b, bpw);
  dwconv_b<<<8192, 256, 0, stream>>>(xb, w_dw, b_dw, dwb);
  gemm_mfma<128, false><<<256, 256, 0, stream>>>(dwb, wp_b, bpw, om);
  gemm_mfma<256, true><<<512, 256, 0, stream>>>(xb, wi_b, b_in, vproj);
  deform_sample_b3<<<4096, 256, 0, stream>>>(vproj, om, dwb /* samp */);
  gemm_mfma<256, false><<<512, 256, 0, stream>>>(dwb, wo_b, b_out, out);
}

// Round 5
// 80.809 us; speedup vs baseline: 4.5348x; 1.1697x over previous
//
#include <hip/hip_runtime.h>

// Problem constants (fixed by reference)
#define HW     4096
#define M_ROWS 32768        // N*H*W
#define OMD    112
#define OMP    128          // padded OM dim (stride, elements)

typedef __attribute__((ext_vector_type(8))) short short8;
typedef __attribute__((ext_vector_type(4))) float f32x4;

__device__ inline unsigned short f2bf(float f) {
  union { float f; unsigned int u; } v; v.f = f;
  unsigned int u = v.u;
  u += 0x7fffu + ((u >> 16) & 1u);      // RNE
  return (unsigned short)(u >> 16);
}
__device__ inline float bf2f(unsigned short h) {
  union { unsigned int u; float f; } v; v.u = ((unsigned int)h) << 16;
  return v.f;
}

// ---------------------------------------------------------------------------
// Fused prep: blocks [0,8192) = depthwise 3x3 (fp32 x in, bf16 dw out) which
// also emits xb = bf16(x); blocks [8192, 8834) = weight/bias conversions.
// ---------------------------------------------------------------------------
__global__ __launch_bounds__(256) void prep_fused(
    const float* __restrict__ x, const float* __restrict__ w_dw,
    const float* __restrict__ b_dw, const float* __restrict__ w_in,
    const float* __restrict__ w_out, const float* __restrict__ w_pw,
    const float* __restrict__ b_pw, unsigned short* __restrict__ xb,
    unsigned short* __restrict__ dwb, unsigned short* __restrict__ wi_b,
    unsigned short* __restrict__ wo_b, unsigned short* __restrict__ wp_b,
    float* __restrict__ bpw_pad) {
  int bid = blockIdx.x;
  int tid = threadIdx.x;
  if (bid < 8192) {
    int idx = bid * 256 + tid;                 // (pixel, c/4): 32768*64
    int c4 = (idx & 63) * 4;
    int pp = idx >> 6;
    int n = pp >> 12;
    int hw = pp & 4095;
    int h = hw >> 6, w = hw & 63;
    float4 bb = *(const float4*)&b_dw[c4];
    float a0 = bb.x, a1 = bb.y, a2 = bb.z, a3 = bb.w;
#pragma unroll
    for (int ky = 0; ky < 3; ++ky) {
      int iy = h + ky - 1;
      if (iy < 0 || iy > 63) continue;
#pragma unroll
      for (int kx = 0; kx < 3; ++kx) {
        int ix = w + kx - 1;
        if (ix < 0 || ix > 63) continue;
        float4 xv = *(const float4*)&x[((size_t)(n << 12) + iy * 64 + ix) * 256 + c4];
        float4 wv = *(const float4*)&w_dw[(ky * 3 + kx) * 256 + c4];
        a0 += xv.x * wv.x;
        a1 += xv.y * wv.y;
        a2 += xv.z * wv.z;
        a3 += xv.w * wv.w;
      }
    }
    ushort4 o;
    o.x = f2bf(a0); o.y = f2bf(a1); o.z = f2bf(a2); o.w = f2bf(a3);
    *(ushort4*)&dwb[(size_t)pp * 256 + c4] = o;
    // xb = bf16(x) for the center pixel (L1-hot reload)
    float4 cv = *(const float4*)&x[(size_t)pp * 256 + c4];
    ushort4 oc;
    oc.x = f2bf(cv.x); oc.y = f2bf(cv.y); oc.z = f2bf(cv.z); oc.w = f2bf(cv.w);
    *(ushort4*)&xb[(size_t)pp * 256 + c4] = oc;
  } else {
    int idx = (bid - 8192) * 256 + tid;
    if (idx < 65536) {
      wi_b[idx] = f2bf(w_in[idx]);
    } else if (idx < 131072) {
      int i = idx - 65536;
      wo_b[i] = f2bf(w_out[i]);
    } else if (idx < 131072 + OMP * 256) {
      int i = idx - 131072;
      int o = i >> 8;
      wp_b[i] = (o < OMD) ? f2bf(w_pw[i]) : (unsigned short)0;
    } else if (idx < 131072 + OMP * 256 + OMP) {
      int i = idx - (131072 + OMP * 256);
      bpw_pad[i] = (i < OMD) ? b_pw[i] : 0.f;
    }
  }
}

// ---------------------------------------------------------------------------
// Merged mid GEMMs (bf16 MFMA, m97 structure; 128x128 tile, BK=32, 4 waves).
// Blocks [0,256):   om[32768,128](bf16) = dwb @ wp_b^T + bpw
// Blocks [256,768): vproj[32768,256](bf16) = xb @ wi_b^T + b_in
// ---------------------------------------------------------------------------
__global__ __launch_bounds__(256) void gemm_mid(
    const unsigned short* __restrict__ dwb, const unsigned short* __restrict__ wp_b,
    const float* __restrict__ bpw, unsigned short* __restrict__ om,
    const unsigned short* __restrict__ xb, const unsigned short* __restrict__ wi_b,
    const float* __restrict__ b_in, unsigned short* __restrict__ vproj) {
  __shared__ __align__(16) unsigned short As[128 * 32];  // 8 KB
  __shared__ __align__(16) unsigned short Bs[128 * 32];  // 8 KB
  int tid = threadIdx.x;
  int wave = tid >> 6, lane = tid & 63;
  int wr = wave >> 1, wc = wave & 1;

  const unsigned short *A, *W;
  const float* bias;
  unsigned short* Cout;
  int NN, colB;
  size_t rowB;
  int bid = blockIdx.x;
  if (bid < 256) {
    int swz = (bid & 7) * 32 + (bid >> 3);     // 256 % 8 == 0, bijective
    A = dwb; W = wp_b; bias = bpw; Cout = om; NN = 128;
    rowB = (size_t)swz * 128; colB = 0;
  } else {
    int b = bid - 256;
    int swz = (b & 7) * 64 + (b >> 3);         // 512 % 8 == 0, bijective
    A = xb; W = wi_b; bias = b_in; Cout = vproj; NN = 256;
    rowB = (size_t)(swz >> 1) * 128; colB = (swz & 1) * 128;
  }

  f32x4 acc[4][4];
#pragma unroll
  for (int m = 0; m < 4; ++m)
#pragma unroll
    for (int n = 0; n < 4; ++n) acc[m][n] = (f32x4)(0.f);

  int arow = lane >> 2;
  int acol = (lane & 3) * 8;

  for (int k0 = 0; k0 < 256; k0 += 32) {
#pragma unroll
    for (int jj = 0; jj < 2; ++jj) {
      int j = wave * 2 + jj;
      const unsigned short* ga = A + (rowB + 16 * j + arow) * 256 + k0 + acol;
      __builtin_amdgcn_global_load_lds(
          (const __attribute__((address_space(1))) unsigned int*)ga,
          (__attribute__((address_space(3))) unsigned int*)(As + j * 512),
          16, 0, 0);
      const unsigned short* gb =
          W + ((size_t)(colB + 16 * j + arow)) * 256 + k0 + acol;
      __builtin_amdgcn_global_load_lds(
          (const __attribute__((address_space(1))) unsigned int*)gb,
          (__attribute__((address_space(3))) unsigned int*)(Bs + j * 512),
          16, 0, 0);
    }
    __syncthreads();

    short8 aF[4], bF[4];
#pragma unroll
    for (int m = 0; m < 4; ++m)
      aF[m] = *(const short8*)&As[(wr * 64 + m * 16 + (lane & 15)) * 32 +
                                  (lane >> 4) * 8];
#pragma unroll
    for (int n = 0; n < 4; ++n)
      bF[n] = *(const short8*)&Bs[(wc * 64 + n * 16 + (lane & 15)) * 32 +
                                  (lane >> 4) * 8];
#pragma unroll
    for (int m = 0; m < 4; ++m)
#pragma unroll
      for (int n = 0; n < 4; ++n)
        acc[m][n] = __builtin_amdgcn_mfma_f32_16x16x32_bf16(
            aF[m], bF[n], acc[m][n], 0, 0, 0);
    __syncthreads();
  }

#pragma unroll
  for (int n = 0; n < 4; ++n) {
    int col = colB + wc * 64 + n * 16 + (lane & 15);
    float bv = bias[col];
#pragma unroll
    for (int m = 0; m < 4; ++m) {
#pragma unroll
      for (int j = 0; j < 4; ++j) {
        size_t row = rowB + wr * 64 + m * 16 + (lane >> 4) * 4 + j;
        Cout[row * NN + col] = f2bf(acc[m][n][j] + bv);
      }
    }
  }
}

// ---------------------------------------------------------------------------
// Final GEMM: out[32768,256](fp32) = samp @ wo_b^T + b_out
// ---------------------------------------------------------------------------
__global__ __launch_bounds__(256) void gemm_out(
    const unsigned short* __restrict__ A, const unsigned short* __restrict__ W,
    const float* __restrict__ bias, float* __restrict__ Cout) {
  __shared__ __align__(16) unsigned short As[128 * 32];
  __shared__ __align__(16) unsigned short Bs[128 * 32];
  int tid = threadIdx.x;
  int wave = tid >> 6, lane = tid & 63;
  int wr = wave >> 1, wc = wave & 1;

  int bid = blockIdx.x;
  int swz = (bid & 7) * 64 + (bid >> 3);
  size_t rowB = (size_t)(swz >> 1) * 128;
  int colB = (swz & 1) * 128;

  f32x4 acc[4][4];
#pragma unroll
  for (int m = 0; m < 4; ++m)
#pragma unroll
    for (int n = 0; n < 4; ++n) acc[m][n] = (f32x4)(0.f);

  int arow = lane >> 2;
  int acol = (lane & 3) * 8;

  for (int k0 = 0; k0 < 256; k0 += 32) {
#pragma unroll
    for (int jj = 0; jj < 2; ++jj) {
      int j = wave * 2 + jj;
      const unsigned short* ga = A + (rowB + 16 * j + arow) * 256 + k0 + acol;
      __builtin_amdgcn_global_load_lds(
          (const __attribute__((address_space(1))) unsigned int*)ga,
          (__attribute__((address_space(3))) unsigned int*)(As + j * 512),
          16, 0, 0);
      const unsigned short* gb =
          W + ((size_t)(colB + 16 * j + arow)) * 256 + k0 + acol;
      __builtin_amdgcn_global_load_lds(
          (const __attribute__((address_space(1))) unsigned int*)gb,
          (__attribute__((address_space(3))) unsigned int*)(Bs + j * 512),
          16, 0, 0);
    }
    __syncthreads();

    short8 aF[4], bF[4];
#pragma unroll
    for (int m = 0; m < 4; ++m)
      aF[m] = *(const short8*)&As[(wr * 64 + m * 16 + (lane & 15)) * 32 +
                                  (lane >> 4) * 8];
#pragma unroll
    for (int n = 0; n < 4; ++n)
      bF[n] = *(const short8*)&Bs[(wc * 64 + n * 16 + (lane & 15)) * 32 +
                                  (lane >> 4) * 8];
#pragma unroll
    for (int m = 0; m < 4; ++m)
#pragma unroll
      for (int n = 0; n < 4; ++n)
        acc[m][n] = __builtin_amdgcn_mfma_f32_16x16x32_bf16(
            aF[m], bF[n], acc[m][n], 0, 0, 0);
    __syncthreads();
  }

#pragma unroll
  for (int n = 0; n < 4; ++n) {
    int col = colB + wc * 64 + n * 16 + (lane & 15);
    float bv = bias[col];
#pragma unroll
    for (int m = 0; m < 4; ++m) {
#pragma unroll
      for (int j = 0; j < 4; ++j) {
        size_t row = rowB + wr * 64 + m * 16 + (lane >> 4) * 4 + j;
        Cout[row * 256 + col] = acc[m][n][j] + bv;
      }
    }
  }
}

// ---------------------------------------------------------------------------
// Deformable bilinear sampling (branchless clamped gathers; bf16 om).
// Block = 4 waves = 8 pixels (2 px/wave; lane owns 8 channels).
// ---------------------------------------------------------------------------
__global__ __launch_bounds__(256) void deform_sample_b3(
    const unsigned short* __restrict__ vproj, const unsigned short* __restrict__ om,
    unsigned short* __restrict__ samp) {
  int bid = blockIdx.x;
  int swz = (bid & 7) * 512 + (bid >> 3);   // 4096 % 8 == 0 -> bijective
  int p0 = swz * 8;

  int tid = threadIdx.x;

  __shared__ __align__(16) float s_w[8][36][4];
  __shared__ __align__(16) int   s_o[8][36][4];

  for (int it = tid; it < 288; it += 256) {
    int pix = it / 36, gk = it % 36;
    int k = gk % 9;
    int p = p0 + pix;
    int h = (p >> 6) & 63, w = p & 63;
    const unsigned short* o = om + (size_t)p * OMP;
    float ox = bf2f(o[gk * 2]), oy = bf2f(o[gk * 2 + 1]);
    float m = bf2f(o[72 + gk]);
    float px = (float)(w + (k % 3) - 1) + ox;
    float py = (float)(h + (k / 3) - 1) + oy;
    float x0f = floorf(px), y0f = floorf(py);
    int x0 = (int)x0f, y0 = (int)y0f;
    float fx = px - x0f, fy = py - y0f;
    bool vx0 = (unsigned)x0 < 64u;
    bool vx1 = (unsigned)(x0 + 1) < 64u;
    bool vy0 = (unsigned)y0 < 64u;
    bool vy1 = (unsigned)(y0 + 1) < 64u;
    s_w[pix][gk][0] = (vy0 && vx0) ? (1.f - fx) * (1.f - fy) * m : 0.f;
    s_w[pix][gk][1] = (vy0 && vx1) ? fx * (1.f - fy) * m : 0.f;
    s_w[pix][gk][2] = (vy1 && vx0) ? (1.f - fx) * fy * m : 0.f;
    s_w[pix][gk][3] = (vy1 && vx1) ? fx * fy * m : 0.f;
    int x0c = min(max(x0, 0), 63), x1c = min(max(x0 + 1, 0), 63);
    int y0c = min(max(y0, 0), 63), y1c = min(max(y0 + 1, 0), 63);
    s_o[pix][gk][0] = (y0c * 64 + x0c) * 512;
    s_o[pix][gk][1] = (y0c * 64 + x1c) * 512;
    s_o[pix][gk][2] = (y1c * 64 + x0c) * 512;
    s_o[pix][gk][3] = (y1c * 64 + x1c) * 512;
  }
  __syncthreads();

  int wave = tid >> 6, lane = tid & 63;
  int pix2 = lane >> 5, sub = lane & 31, g = sub >> 3;
  int pixb = wave * 2 + pix2;
  int p = p0 + pixb;
  int n = p0 >> 12;
  const char* vb = (const char*)(vproj + (((size_t)n << 12)) * 256);
  int choff = sub * 16;

  float acc[8];
#pragma unroll
  for (int j = 0; j < 8; ++j) acc[j] = 0.f;

#pragma unroll
  for (int k = 0; k < 9; ++k) {
    int gk = g * 9 + k;
    float4 wv = *(const float4*)s_w[pixb][gk];
    int4 ov = *(const int4*)s_o[pixb][gk];
#pragma unroll
    for (int c = 0; c < 4; ++c) {
      int off = (c == 0) ? ov.x : (c == 1) ? ov.y : (c == 2) ? ov.z : ov.w;
      float wgt = (c == 0) ? wv.x : (c == 1) ? wv.y : (c == 2) ? wv.z : wv.w;
      short8 v = *(const short8*)(vb + off + choff);
#pragma unroll
      for (int j = 0; j < 8; ++j)
        acc[j] += wgt * bf2f((unsigned short)v[j]);
    }
  }

  union { unsigned short s[8]; short8 v8; } o;
#pragma unroll
  for (int j = 0; j < 8; ++j) o.s[j] = f2bf(acc[j]);
  *(short8*)&samp[(size_t)p * 256 + sub * 8] = o.v8;
}

// ---------------------------------------------------------------------------
extern "C" void kernel_launch(void* const* d_in, const int* in_sizes, int n_in,
                              void* d_out, int out_size, void* d_ws,
                              size_t ws_size, hipStream_t stream) {
  const float* x     = (const float*)d_in[0];
  const float* w_in  = (const float*)d_in[3];
  const float* b_in  = (const float*)d_in[4];
  const float* w_out = (const float*)d_in[5];
  const float* b_out = (const float*)d_in[6];
  const float* w_dw  = (const float*)d_in[7];
  const float* b_dw  = (const float*)d_in[8];
  const float* w_pw  = (const float*)d_in[9];
  const float* b_pw  = (const float*)d_in[10];
  float* out = (float*)d_out;
  char* ws = (char*)d_ws;

  unsigned short* xb    = (unsigned short*)(ws);                  // 16 MB
  unsigned short* dwb   = (unsigned short*)(ws + (16u << 20));    // 16 MB (dw, reused as samp)
  unsigned short* vproj = (unsigned short*)(ws + (32u << 20));    // 16 MB
  unsigned short* om    = (unsigned short*)(ws + (48u << 20));    // 8 MB (bf16, stride 128)
  unsigned short* wi_b  = (unsigned short*)(ws + (56u << 20));    // 128 KB
  unsigned short* wo_b  = (unsigned short*)(ws + (56u << 20) + (128u << 10));
  unsigned short* wp_b  = (unsigned short*)(ws + (56u << 20) + (256u << 10)); // 64 KB
  float*          bpw   = (float*)(ws + (56u << 20) + (320u << 10));          // 512 B

  prep_fused<<<8834, 256, 0, stream>>>(x, w_dw, b_dw, w_in, w_out, w_pw, b_pw,
                                       xb, dwb, wi_b, wo_b, wp_b, bpw);
  gemm_mid<<<768, 256, 0, stream>>>(dwb, wp_b, bpw, om, xb, wi_b, b_in, vproj);
  deform_sample_b3<<<4096, 256, 0, stream>>>(vproj, om, dwb /* samp */);
  gemm_out<<<512, 256, 0, stream>>>(dwb, wo_b, b_out, out);
}